// Round 1
// baseline (6843.243 us; speedup 1.0000x reference)
//
#include <hip/hip_runtime.h>
#include <math.h>

#define NN 50000
#define NE 800000

#define LRELU(v) ((v) > 0.f ? (v) : 0.2f * (v))

// ---------------------------------------------------------------------------
// GEMM: out = A @ W + b   (A [N,K] row-major, W [K,256], bias [256])
// Two weight matrices per launch via blockIdx.y (xl and xr share the A tile
// schedule). BM=64 rows, BN=256 (full), BK=32. 256 threads.
// ---------------------------------------------------------------------------
__global__ __launch_bounds__(256)
void gemm_bias2(const float* __restrict__ A,
                const float* __restrict__ W0, const float* __restrict__ b0,
                float* __restrict__ out0,
                const float* __restrict__ W1, const float* __restrict__ b1,
                float* __restrict__ out1,
                int N, int K) {
  const float* W    = blockIdx.y ? W1 : W0;
  const float* bias = blockIdx.y ? b1 : b0;
  float*       out  = blockIdx.y ? out1 : out0;

  __shared__ float As[32][68];   // k-major (transposed), padded
  __shared__ float Bs[32][256];

  const int tid  = threadIdx.x;
  const int c4   = (tid & 63) * 4;   // output col group
  const int rg   = tid >> 6;         // wave id -> rows rg*16..rg*16+15
  const int row0 = blockIdx.x * 64;

  float acc[16][4];
#pragma unroll
  for (int i = 0; i < 16; ++i)
#pragma unroll
    for (int j = 0; j < 4; ++j) acc[i][j] = 0.f;

  for (int k0 = 0; k0 < K; k0 += 32) {
    // A tile 64 rows x 32 k, store transposed As[k][row]
#pragma unroll
    for (int p = 0; p < 2; ++p) {
      const int r  = p * 32 + (tid >> 3);
      const int kq = (tid & 7) * 4;
      float4 v = make_float4(0.f, 0.f, 0.f, 0.f);
      const int grow = row0 + r;
      if (grow < N) v = *(const float4*)(A + (size_t)grow * K + k0 + kq);
      As[kq + 0][r] = v.x; As[kq + 1][r] = v.y;
      As[kq + 2][r] = v.z; As[kq + 3][r] = v.w;
    }
    // B tile 32 x 256, contiguous
#pragma unroll
    for (int p = 0; p < 8; ++p) {
      const int lin = p * 1024 + tid * 4;
      const int kk = lin >> 8, cc = lin & 255;
      *(float4*)&Bs[kk][cc] = *(const float4*)(W + (size_t)(k0 + kk) * 256 + cc);
    }
    __syncthreads();
#pragma unroll
    for (int kk = 0; kk < 32; ++kk) {
      const float4 b = *(const float4*)&Bs[kk][c4];
      const float bb[4] = {b.x, b.y, b.z, b.w};
#pragma unroll
      for (int q = 0; q < 4; ++q) {
        const float4 a = *(const float4*)&As[kk][rg * 16 + q * 4];
        const float aa[4] = {a.x, a.y, a.z, a.w};
#pragma unroll
        for (int m = 0; m < 4; ++m)
#pragma unroll
          for (int j = 0; j < 4; ++j) acc[q * 4 + m][j] += aa[m] * bb[j];
      }
    }
    __syncthreads();
  }

  const float4 bv = *(const float4*)(bias + c4);
#pragma unroll
  for (int i = 0; i < 16; ++i) {
    const int row = row0 + rg * 16 + i;
    if (row < N) {
      float4 o;
      o.x = acc[i][0] + bv.x; o.y = acc[i][1] + bv.y;
      o.z = acc[i][2] + bv.z; o.w = acc[i][3] + bv.w;
      *(float4*)(out + (size_t)row * 256 + c4) = o;
    }
  }
}

// ---------------------------------------------------------------------------
// Edge kernel: per edge e, per head h:
//   logit = dot(att[h], lrelu(xl[src] + xr[dst] + edge_attr[e]@We))
//   elog[e,h] = exp(logit);  denom[dst,h] += elog  (atomic)
// Tile: 64 edges x 128 cols (2 heads) per block; blockIdx.y picks col half.
// ee computed as fp32 LDS-tiled GEMM fused with epilogue (never materialized).
// ---------------------------------------------------------------------------
__global__ __launch_bounds__(256)
void edge_logits(const float* __restrict__ xl, const float* __restrict__ xr,
                 const float* __restrict__ ea, const float* __restrict__ We,
                 const float* __restrict__ att, const int* __restrict__ src,
                 const int* __restrict__ dst, float* __restrict__ elog,
                 float* __restrict__ denom) {
  __shared__ float As[64][68];    // edge_attr tile, k-major [k][edge]
  __shared__ float Bs[64][128];   // We column half
  __shared__ float satt[128];
  __shared__ int ssrc[64], sdst[64];

  const int tid = threadIdx.x;
  const int e0  = blockIdx.x * 64;
  const int ch  = blockIdx.y;     // col half -> heads 2*ch, 2*ch+1

  // edge_attr tile 64 x 64, transposed into As
#pragma unroll
  for (int p = 0; p < 4; ++p) {
    const int lin = p * 1024 + tid * 4;
    const int el = lin >> 6, kq = lin & 63;
    const float4 v = *(const float4*)(ea + (size_t)(e0 + el) * 64 + kq);
    As[kq + 0][el] = v.x; As[kq + 1][el] = v.y;
    As[kq + 2][el] = v.z; As[kq + 3][el] = v.w;
  }
  // We half 64 x 128
#pragma unroll
  for (int p = 0; p < 8; ++p) {
    const int lin = p * 1024 + tid * 4;
    const int kk = lin >> 7, cc = lin & 127;
    *(float4*)&Bs[kk][cc] = *(const float4*)(We + (size_t)kk * 256 + ch * 128 + cc);
  }
  if (tid < 128) satt[tid] = att[ch * 128 + tid];
  if (tid < 64) { ssrc[tid] = src[e0 + tid]; sdst[tid] = dst[e0 + tid]; }
  __syncthreads();

  const int c4 = (tid & 31) * 4;  // col within half (0..124)
  const int rg = tid >> 5;        // 0..7 -> edges rg*8..rg*8+7

  float acc[8][4];
#pragma unroll
  for (int i = 0; i < 8; ++i)
#pragma unroll
    for (int j = 0; j < 4; ++j) acc[i][j] = 0.f;

#pragma unroll
  for (int kk = 0; kk < 64; ++kk) {
    const float4 b = *(const float4*)&Bs[kk][c4];
    const float bb[4] = {b.x, b.y, b.z, b.w};
#pragma unroll
    for (int q = 0; q < 2; ++q) {
      const float4 a = *(const float4*)&As[kk][rg * 8 + q * 4];
      const float aa[4] = {a.x, a.y, a.z, a.w};
#pragma unroll
      for (int m = 0; m < 4; ++m)
#pragma unroll
        for (int j = 0; j < 4; ++j) acc[q * 4 + m][j] += aa[m] * bb[j];
    }
  }

  const int lane = tid & 63;
  const int hl   = (lane & 31) >> 4;             // local head (0/1)
  const float4 attv = *(const float4*)&satt[hl * 64 + (c4 & 63)];

  float plog[8];
#pragma unroll
  for (int i = 0; i < 8; ++i) {
    const int el = rg * 8 + i;
    const int s = ssrc[el], d = sdst[el];
    const float4 xlv = *(const float4*)(xl + (size_t)s * 256 + ch * 128 + c4);
    const float4 xrv = *(const float4*)(xr + (size_t)d * 256 + ch * 128 + c4);
    float m0 = LRELU(acc[i][0] + xlv.x + xrv.x);
    float m1 = LRELU(acc[i][1] + xlv.y + xrv.y);
    float m2 = LRELU(acc[i][2] + xlv.z + xrv.z);
    float m3 = LRELU(acc[i][3] + xlv.w + xrv.w);
    plog[i] = m0 * attv.x + m1 * attv.y + m2 * attv.z + m3 * attv.w;
  }
  // reduce across the 16 lanes holding this (edge, head)'s col slices
#pragma unroll
  for (int i = 0; i < 8; ++i) {
#pragma unroll
    for (int s = 8; s >= 1; s >>= 1) plog[i] += __shfl_xor(plog[i], s, 16);
  }
  if ((lane & 15) == 0) {
    const int h = ch * 2 + hl;
#pragma unroll
    for (int i = 0; i < 8; ++i) {
      const int el = rg * 8 + i;
      const float ev = expf(plog[i]);
      elog[(size_t)(e0 + el) * 4 + h] = ev;
      atomicAdd(&denom[(size_t)sdst[el] * 4 + h], ev);
    }
  }
}

// out[n*256+c] = bias[c]
__global__ __launch_bounds__(256)
void node_init(float* __restrict__ out, const float* __restrict__ bias, int n) {
  const int g = blockIdx.x * 256 + threadIdx.x;
  if (g < n) out[g] = bias[g & 255];
}

// out[dst] += (elog/denom[dst]) * xl[src]   — one wave per edge
__global__ __launch_bounds__(256)
void scatter_alpha(const float* __restrict__ xl, const float* __restrict__ elog,
                   const float* __restrict__ denom, const int* __restrict__ src,
                   const int* __restrict__ dst, float* __restrict__ out) {
  const int gid = blockIdx.x * 256 + threadIdx.x;
  const int e = gid >> 6;
  if (e >= NE) return;
  const int lane = threadIdx.x & 63;
  const int s = src[e], d = dst[e];
  const int h = lane >> 4;
  const float alpha = elog[(size_t)e * 4 + h] /
                      (denom[(size_t)d * 4 + h] + 1e-16f);
  const int c = lane * 4;
  const float4 v = *(const float4*)(xl + (size_t)s * 256 + c);
  float* o = out + (size_t)d * 256 + c;
  atomicAdd(o + 0, alpha * v.x);
  atomicAdd(o + 1, alpha * v.y);
  atomicAdd(o + 2, alpha * v.z);
  atomicAdd(o + 3, alpha * v.w);
}

extern "C" void kernel_launch(void* const* d_in, const int* in_sizes, int n_in,
                              void* d_out, int out_size, void* d_ws, size_t ws_size,
                              hipStream_t stream) {
  const float* x    = (const float*)d_in[0];
  const int*   ei   = (const int*)d_in[1];
  const float* ea   = (const float*)d_in[2];
  const float* Wl1  = (const float*)d_in[3];
  const float* bl1  = (const float*)d_in[4];
  const float* Wr1  = (const float*)d_in[5];
  const float* br1  = (const float*)d_in[6];
  const float* We1  = (const float*)d_in[7];
  const float* att1 = (const float*)d_in[8];
  const float* bias1= (const float*)d_in[9];
  const float* Wl2  = (const float*)d_in[10];
  const float* bl2  = (const float*)d_in[11];
  const float* Wr2  = (const float*)d_in[12];
  const float* br2  = (const float*)d_in[13];
  const float* We2  = (const float*)d_in[14];
  const float* att2 = (const float*)d_in[15];
  const float* bias2= (const float*)d_in[16];

  float* out = (float*)d_out;
  float* ws  = (float*)d_ws;

  float* xl    = ws;                              // 12.8M floats
  float* xr    = xl + (size_t)NN * 256;           // 12.8M
  float* elog  = xr + (size_t)NN * 256;           // 3.2M
  float* denom = elog + (size_t)NE * 4;           // 0.2M
  float* h1    = out;  // d_out doubles as h1; fully consumed before re-init

  const int* src = ei;
  const int* dst = ei + NE;

  const dim3 ggrid((NN + 63) / 64, 2);
  const dim3 egrid(NE / 64, 2);
  const int igrid = (NN * 256 + 255) / 256;
  const int sgrid = (NE * 64) / 256;

  // ---- layer 1 ----
  gemm_bias2<<<ggrid, 256, 0, stream>>>(x, Wl1, bl1, xl, Wr1, br1, xr, NN, 128);
  hipMemsetAsync(denom, 0, (size_t)NN * 4 * sizeof(float), stream);
  edge_logits<<<egrid, 256, 0, stream>>>(xl, xr, ea, We1, att1, src, dst, elog, denom);
  node_init<<<igrid, 256, 0, stream>>>(h1, bias1, NN * 256);
  scatter_alpha<<<sgrid, 256, 0, stream>>>(xl, elog, denom, src, dst, h1);

  // ---- layer 2 ----
  gemm_bias2<<<ggrid, 256, 0, stream>>>(h1, Wl2, bl2, xl, Wr2, br2, xr, NN, 256);
  hipMemsetAsync(denom, 0, (size_t)NN * 4 * sizeof(float), stream);
  edge_logits<<<egrid, 256, 0, stream>>>(xl, xr, ea, We2, att2, src, dst, elog, denom);
  node_init<<<igrid, 256, 0, stream>>>(out, bias2, NN * 256);
  scatter_alpha<<<sgrid, 256, 0, stream>>>(xl, elog, denom, src, dst, out);
}

// Round 2
// 1846.761 us; speedup vs baseline: 3.7055x; 3.7055x over previous
//
#include <hip/hip_runtime.h>
#include <math.h>

#define NN 50000
#define NE 800000

#define LRELU(v) ((v) > 0.f ? (v) : 0.2f * (v))

// ---------------------------------------------------------------------------
// GEMM: out = A @ W + b   (A [N,K] row-major, W [K,256], bias [256])
// Two weight matrices per launch via blockIdx.y. BM=64, BN=256, BK=32.
// ---------------------------------------------------------------------------
__global__ __launch_bounds__(256)
void gemm_bias2(const float* __restrict__ A,
                const float* __restrict__ W0, const float* __restrict__ b0,
                float* __restrict__ out0,
                const float* __restrict__ W1, const float* __restrict__ b1,
                float* __restrict__ out1,
                int N, int K) {
  const float* W    = blockIdx.y ? W1 : W0;
  const float* bias = blockIdx.y ? b1 : b0;
  float*       out  = blockIdx.y ? out1 : out0;

  __shared__ float As[32][68];   // k-major (transposed), padded
  __shared__ float Bs[32][256];

  const int tid  = threadIdx.x;
  const int c4   = (tid & 63) * 4;
  const int rg   = tid >> 6;
  const int row0 = blockIdx.x * 64;

  float acc[16][4];
#pragma unroll
  for (int i = 0; i < 16; ++i)
#pragma unroll
    for (int j = 0; j < 4; ++j) acc[i][j] = 0.f;

  for (int k0 = 0; k0 < K; k0 += 32) {
#pragma unroll
    for (int p = 0; p < 2; ++p) {
      const int r  = p * 32 + (tid >> 3);
      const int kq = (tid & 7) * 4;
      float4 v = make_float4(0.f, 0.f, 0.f, 0.f);
      const int grow = row0 + r;
      if (grow < N) v = *(const float4*)(A + (size_t)grow * K + k0 + kq);
      As[kq + 0][r] = v.x; As[kq + 1][r] = v.y;
      As[kq + 2][r] = v.z; As[kq + 3][r] = v.w;
    }
#pragma unroll
    for (int p = 0; p < 8; ++p) {
      const int lin = p * 1024 + tid * 4;
      const int kk = lin >> 8, cc = lin & 255;
      *(float4*)&Bs[kk][cc] = *(const float4*)(W + (size_t)(k0 + kk) * 256 + cc);
    }
    __syncthreads();
#pragma unroll
    for (int kk = 0; kk < 32; ++kk) {
      const float4 b = *(const float4*)&Bs[kk][c4];
      const float bb[4] = {b.x, b.y, b.z, b.w};
#pragma unroll
      for (int q = 0; q < 4; ++q) {
        const float4 a = *(const float4*)&As[kk][rg * 16 + q * 4];
        const float aa[4] = {a.x, a.y, a.z, a.w};
#pragma unroll
        for (int m = 0; m < 4; ++m)
#pragma unroll
          for (int j = 0; j < 4; ++j) acc[q * 4 + m][j] += aa[m] * bb[j];
      }
    }
    __syncthreads();
  }

  const float4 bv = *(const float4*)(bias + c4);
#pragma unroll
  for (int i = 0; i < 16; ++i) {
    const int row = row0 + rg * 16 + i;
    if (row < N) {
      float4 o;
      o.x = acc[i][0] + bv.x; o.y = acc[i][1] + bv.y;
      o.z = acc[i][2] + bv.z; o.w = acc[i][3] + bv.w;
      *(float4*)(out + (size_t)row * 256 + c4) = o;
    }
  }
}

// ---------------------------------------------------------------------------
// Edge kernel: logits -> elog = exp(logit), denom[dst,h] += elog (atomic).
// 64 edges x 128 cols (2 heads) per block; blockIdx.y = col half.
// ---------------------------------------------------------------------------
__global__ __launch_bounds__(256)
void edge_logits(const float* __restrict__ xl, const float* __restrict__ xr,
                 const float* __restrict__ ea, const float* __restrict__ We,
                 const float* __restrict__ att, const int* __restrict__ src,
                 const int* __restrict__ dst, float* __restrict__ elog,
                 float* __restrict__ denom) {
  __shared__ float As[64][68];
  __shared__ float Bs[64][128];
  __shared__ float satt[128];
  __shared__ int ssrc[64], sdst[64];

  const int tid = threadIdx.x;
  const int e0  = blockIdx.x * 64;
  const int ch  = blockIdx.y;

#pragma unroll
  for (int p = 0; p < 4; ++p) {
    const int lin = p * 1024 + tid * 4;
    const int el = lin >> 6, kq = lin & 63;
    const float4 v = *(const float4*)(ea + (size_t)(e0 + el) * 64 + kq);
    As[kq + 0][el] = v.x; As[kq + 1][el] = v.y;
    As[kq + 2][el] = v.z; As[kq + 3][el] = v.w;
  }
#pragma unroll
  for (int p = 0; p < 8; ++p) {
    const int lin = p * 1024 + tid * 4;
    const int kk = lin >> 7, cc = lin & 127;
    *(float4*)&Bs[kk][cc] = *(const float4*)(We + (size_t)kk * 256 + ch * 128 + cc);
  }
  if (tid < 128) satt[tid] = att[ch * 128 + tid];
  if (tid < 64) { ssrc[tid] = src[e0 + tid]; sdst[tid] = dst[e0 + tid]; }
  __syncthreads();

  const int c4 = (tid & 31) * 4;
  const int rg = tid >> 5;

  float acc[8][4];
#pragma unroll
  for (int i = 0; i < 8; ++i)
#pragma unroll
    for (int j = 0; j < 4; ++j) acc[i][j] = 0.f;

#pragma unroll
  for (int kk = 0; kk < 64; ++kk) {
    const float4 b = *(const float4*)&Bs[kk][c4];
    const float bb[4] = {b.x, b.y, b.z, b.w};
#pragma unroll
    for (int q = 0; q < 2; ++q) {
      const float4 a = *(const float4*)&As[kk][rg * 8 + q * 4];
      const float aa[4] = {a.x, a.y, a.z, a.w};
#pragma unroll
      for (int m = 0; m < 4; ++m)
#pragma unroll
        for (int j = 0; j < 4; ++j) acc[q * 4 + m][j] += aa[m] * bb[j];
    }
  }

  const int lane = tid & 63;
  const int hl   = (lane & 31) >> 4;
  const float4 attv = *(const float4*)&satt[hl * 64 + (c4 & 63)];

  float plog[8];
#pragma unroll
  for (int i = 0; i < 8; ++i) {
    const int el = rg * 8 + i;
    const int s = ssrc[el], d = sdst[el];
    const float4 xlv = *(const float4*)(xl + (size_t)s * 256 + ch * 128 + c4);
    const float4 xrv = *(const float4*)(xr + (size_t)d * 256 + ch * 128 + c4);
    float m0 = LRELU(acc[i][0] + xlv.x + xrv.x);
    float m1 = LRELU(acc[i][1] + xlv.y + xrv.y);
    float m2 = LRELU(acc[i][2] + xlv.z + xrv.z);
    float m3 = LRELU(acc[i][3] + xlv.w + xrv.w);
    plog[i] = m0 * attv.x + m1 * attv.y + m2 * attv.z + m3 * attv.w;
  }
#pragma unroll
  for (int i = 0; i < 8; ++i) {
#pragma unroll
    for (int s = 8; s >= 1; s >>= 1) plog[i] += __shfl_xor(plog[i], s, 16);
  }
  if ((lane & 15) == 0) {
    const int h = ch * 2 + hl;
#pragma unroll
    for (int i = 0; i < 8; ++i) {
      const int el = rg * 8 + i;
      const float ev = expf(plog[i]);
      elog[(size_t)(e0 + el) * 4 + h] = ev;
      atomicAdd(&denom[(size_t)sdst[el] * 4 + h], ev);
    }
  }
}

// ---------------------------------------------------------------------------
// CSR build: histogram -> exclusive scan -> bucket fill
// ---------------------------------------------------------------------------
__global__ __launch_bounds__(256)
void dst_hist(const int* __restrict__ dst, int* __restrict__ cnt) {
  const int e = blockIdx.x * 256 + threadIdx.x;
  if (e < NE) atomicAdd(&cnt[dst[e]], 1);
}

// single block, 1024 threads: exclusive scan of cnt[0..n) -> row_start, cur
__global__ __launch_bounds__(1024)
void exscan(int* __restrict__ cnt, int* __restrict__ row_start,
            int* __restrict__ cur, int n) {
  __shared__ int buf[1024];
  __shared__ int carry;
  if (threadIdx.x == 0) carry = 0;
  __syncthreads();
  for (int base = 0; base < n; base += 1024) {
    const int i = base + threadIdx.x;
    const int v = (i < n) ? cnt[i] : 0;
    buf[threadIdx.x] = v;
    __syncthreads();
    for (int off = 1; off < 1024; off <<= 1) {
      const int t = (threadIdx.x >= off) ? buf[threadIdx.x - off] : 0;
      __syncthreads();
      buf[threadIdx.x] += t;
      __syncthreads();
    }
    const int excl = buf[threadIdx.x] - v + carry;
    if (i < n) { row_start[i] = excl; cur[i] = excl; }
    __syncthreads();
    if (threadIdx.x == 1023) carry += buf[1023];
    __syncthreads();
  }
  if (threadIdx.x == 0) row_start[n] = carry;
}

__global__ __launch_bounds__(256)
void bucket_fill(const int* __restrict__ dst, int* __restrict__ cur,
                 int* __restrict__ eid) {
  const int e = blockIdx.x * 256 + threadIdx.x;
  if (e < NE) {
    const int p = atomicAdd(&cur[dst[e]], 1);
    eid[p] = e;
  }
}

// ---------------------------------------------------------------------------
// Aggregation (gather): one wave per dst node, 4 nodes per block.
// out[d] = bias + sum_e alpha[e,h] * xl[src[e]]
// ---------------------------------------------------------------------------
__global__ __launch_bounds__(256)
void aggregate(const float* __restrict__ xl, const float* __restrict__ elog,
               const float* __restrict__ denom, const int* __restrict__ eid,
               const int* __restrict__ row_start, const int* __restrict__ src,
               const float* __restrict__ bias, float* __restrict__ out) {
  const int wid  = threadIdx.x >> 6;
  const int lane = threadIdx.x & 63;
  const int d    = blockIdx.x * 4 + wid;
  if (d >= NN) return;
  const int h = lane >> 4;           // head for my 4 cols
  const int c = lane * 4;
  const float invden = 1.f / (denom[(size_t)d * 4 + h] + 1e-16f);
  float4 acc = *(const float4*)(bias + c);
  const int beg = row_start[d], end = row_start[d + 1];
  for (int i = beg; i < end; ++i) {
    const int e = eid[i];
    const int s = src[e];
    const float a = elog[(size_t)e * 4 + h] * invden;
    const float4 v = *(const float4*)(xl + (size_t)s * 256 + c);
    acc.x += a * v.x; acc.y += a * v.y;
    acc.z += a * v.z; acc.w += a * v.w;
  }
  *(float4*)(out + (size_t)d * 256 + c) = acc;
}

extern "C" void kernel_launch(void* const* d_in, const int* in_sizes, int n_in,
                              void* d_out, int out_size, void* d_ws, size_t ws_size,
                              hipStream_t stream) {
  const float* x    = (const float*)d_in[0];
  const int*   ei   = (const int*)d_in[1];
  const float* ea   = (const float*)d_in[2];
  const float* Wl1  = (const float*)d_in[3];
  const float* bl1  = (const float*)d_in[4];
  const float* Wr1  = (const float*)d_in[5];
  const float* br1  = (const float*)d_in[6];
  const float* We1  = (const float*)d_in[7];
  const float* att1 = (const float*)d_in[8];
  const float* bias1= (const float*)d_in[9];
  const float* Wl2  = (const float*)d_in[10];
  const float* bl2  = (const float*)d_in[11];
  const float* Wr2  = (const float*)d_in[12];
  const float* br2  = (const float*)d_in[13];
  const float* We2  = (const float*)d_in[14];
  const float* att2 = (const float*)d_in[15];
  const float* bias2= (const float*)d_in[16];

  float* out = (float*)d_out;
  float* ws  = (float*)d_ws;

  float* xl    = ws;
  float* xr    = xl + (size_t)NN * 256;
  float* elog  = xr + (size_t)NN * 256;
  float* denom = elog + (size_t)NE * 4;
  int*   cur       = (int*)(denom + (size_t)NN * 4);  // histogram + cursor
  int*   row_start = cur + NN;                        // NN+1 entries
  int*   eid       = row_start + NN + 1;              // NE entries
  float* h1    = out;  // d_out doubles as h1; fully consumed before layer-2 agg

  const int* src = ei;
  const int* dst = ei + NE;

  const dim3 ggrid((NN + 63) / 64, 2);
  const dim3 egrid(NE / 64, 2);
  const int  epb   = (NE + 255) / 256;
  const int  agrid = (NN + 3) / 4;

  // ---- CSR build (shared by both layers) ----
  hipMemsetAsync(cur, 0, NN * sizeof(int), stream);
  dst_hist<<<epb, 256, 0, stream>>>(dst, cur);
  exscan<<<1, 1024, 0, stream>>>(cur, row_start, cur, NN);
  bucket_fill<<<epb, 256, 0, stream>>>(dst, cur, eid);

  // ---- layer 1 ----
  gemm_bias2<<<ggrid, 256, 0, stream>>>(x, Wl1, bl1, xl, Wr1, br1, xr, NN, 128);
  hipMemsetAsync(denom, 0, (size_t)NN * 4 * sizeof(float), stream);
  edge_logits<<<egrid, 256, 0, stream>>>(xl, xr, ea, We1, att1, src, dst, elog, denom);
  aggregate<<<agrid, 256, 0, stream>>>(xl, elog, denom, eid, row_start, src, bias1, h1);

  // ---- layer 2 ----
  gemm_bias2<<<ggrid, 256, 0, stream>>>(h1, Wl2, bl2, xl, Wr2, br2, xr, NN, 256);
  hipMemsetAsync(denom, 0, (size_t)NN * 4 * sizeof(float), stream);
  edge_logits<<<egrid, 256, 0, stream>>>(xl, xr, ea, We2, att2, src, dst, elog, denom);
  aggregate<<<agrid, 256, 0, stream>>>(xl, elog, denom, eid, row_start, src, bias2, out);
}

// Round 3
// 1542.453 us; speedup vs baseline: 4.4366x; 1.1973x over previous
//
#include <hip/hip_runtime.h>
#include <math.h>

#define NN 50000
#define NE 800000

#define LRELU(v) ((v) > 0.f ? (v) : 0.2f * (v))

typedef __attribute__((ext_vector_type(4))) float f32x4;
typedef __attribute__((ext_vector_type(8))) short bf16x8;

static __device__ __forceinline__ float bf2f(unsigned short u) {
  union { unsigned int i; float f; } c; c.i = ((unsigned int)u) << 16; return c.f;
}
static __device__ __forceinline__ unsigned short f2bf(float f) {
  union { float f; unsigned int i; } c; c.f = f;
  unsigned int r = c.i + 0x7fff + ((c.i >> 16) & 1);   // RNE
  return (unsigned short)(r >> 16);
}

// ---------------------------------------------------------------------------
// GEMM: out = A @ W + b. Writes fp32 (xl path only) + bf16 copy for gathers.
// blockIdx.y: 0 -> (W0,b0) xl (fp32+bf16), 1 -> (W1,b1) xr (bf16 only).
// ---------------------------------------------------------------------------
__global__ __launch_bounds__(256)
void gemm_bias2(const float* __restrict__ A,
                const float* __restrict__ W0, const float* __restrict__ b0,
                float* __restrict__ outf, unsigned short* __restrict__ outb0,
                const float* __restrict__ W1, const float* __restrict__ b1,
                unsigned short* __restrict__ outb1,
                int N, int K) {
  const float* W    = blockIdx.y ? W1 : W0;
  const float* bias = blockIdx.y ? b1 : b0;
  unsigned short* outb = blockIdx.y ? outb1 : outb0;
  float* outf_ = blockIdx.y ? nullptr : outf;

  __shared__ float As[32][68];
  __shared__ float Bs[32][256];

  const int tid  = threadIdx.x;
  const int c4   = (tid & 63) * 4;
  const int rg   = tid >> 6;
  const int row0 = blockIdx.x * 64;

  float acc[16][4];
#pragma unroll
  for (int i = 0; i < 16; ++i)
#pragma unroll
    for (int j = 0; j < 4; ++j) acc[i][j] = 0.f;

  for (int k0 = 0; k0 < K; k0 += 32) {
#pragma unroll
    for (int p = 0; p < 2; ++p) {
      const int r  = p * 32 + (tid >> 3);
      const int kq = (tid & 7) * 4;
      float4 v = make_float4(0.f, 0.f, 0.f, 0.f);
      const int grow = row0 + r;
      if (grow < N) v = *(const float4*)(A + (size_t)grow * K + k0 + kq);
      As[kq + 0][r] = v.x; As[kq + 1][r] = v.y;
      As[kq + 2][r] = v.z; As[kq + 3][r] = v.w;
    }
#pragma unroll
    for (int p = 0; p < 8; ++p) {
      const int lin = p * 1024 + tid * 4;
      const int kk = lin >> 8, cc = lin & 255;
      *(float4*)&Bs[kk][cc] = *(const float4*)(W + (size_t)(k0 + kk) * 256 + cc);
    }
    __syncthreads();
#pragma unroll
    for (int kk = 0; kk < 32; ++kk) {
      const float4 b = *(const float4*)&Bs[kk][c4];
      const float bb[4] = {b.x, b.y, b.z, b.w};
#pragma unroll
      for (int q = 0; q < 4; ++q) {
        const float4 a = *(const float4*)&As[kk][rg * 16 + q * 4];
        const float aa[4] = {a.x, a.y, a.z, a.w};
#pragma unroll
        for (int m = 0; m < 4; ++m)
#pragma unroll
          for (int j = 0; j < 4; ++j) acc[q * 4 + m][j] += aa[m] * bb[j];
      }
    }
    __syncthreads();
  }

  const float4 bv = *(const float4*)(bias + c4);
#pragma unroll
  for (int i = 0; i < 16; ++i) {
    const int row = row0 + rg * 16 + i;
    if (row < N) {
      float4 o;
      o.x = acc[i][0] + bv.x; o.y = acc[i][1] + bv.y;
      o.z = acc[i][2] + bv.z; o.w = acc[i][3] + bv.w;
      if (outf_) *(float4*)(outf_ + (size_t)row * 256 + c4) = o;
      ushort4 ob;
      ob.x = f2bf(o.x); ob.y = f2bf(o.y); ob.z = f2bf(o.z); ob.w = f2bf(o.w);
      *(ushort4*)(outb + (size_t)row * 256 + c4) = ob;
    }
  }
}

// ---------------------------------------------------------------------------
// WeT prep: wet[c*64+k] = bf16(We[k*256+c]); blockIdx.y picks layer.
// ---------------------------------------------------------------------------
__global__ __launch_bounds__(256)
void conv_wet(const float* __restrict__ We1, unsigned short* __restrict__ wet1,
              const float* __restrict__ We2, unsigned short* __restrict__ wet2) {
  const float* We = blockIdx.y ? We2 : We1;
  unsigned short* wet = blockIdx.y ? wet2 : wet1;
  const int idx = blockIdx.x * 256 + threadIdx.x;   // 0..16383
  const int k = idx >> 8, c = idx & 255;
  wet[c * 64 + k] = f2bf(We[(size_t)k * 256 + c]);
}

// ---------------------------------------------------------------------------
// Edge kernel (MFMA): per block 64 edges x 256 cols, 4 waves x 16 edges.
// ee = ea@We via mfma_f32_16x16x32_bf16 (A from ea fp32 on-the-fly, B from
// WeT bf16 via L1/L2). Epilogue: gather xlb/xrb (bf16), lrelu, att-dot,
// 16-lane shfl reduce, exp, elog write + denom atomic. No LDS.
// ---------------------------------------------------------------------------
__global__ __launch_bounds__(256)
void edge_logits_mfma(const float* __restrict__ ea,
                      const unsigned short* __restrict__ wet,  // [256][64]
                      const unsigned short* __restrict__ xlb,  // [NN][256]
                      const unsigned short* __restrict__ xrb,
                      const float* __restrict__ att,           // [256]
                      const int* __restrict__ src, const int* __restrict__ dst,
                      float* __restrict__ elog, float* __restrict__ denom) {
  const int tid = threadIdx.x;
  const int w = tid >> 6, l = tid & 63;
  const int lg = l >> 4, lid = l & 15;
  const int e0 = blockIdx.x * 64 + w * 16;   // wave's 16 edges

  // A frags: row e0+lid, k = 32t + 8*lg + j  (convert fp32 -> bf16)
  const float* ap = ea + (size_t)(e0 + lid) * 64 + lg * 8;
  const float4 a00 = *(const float4*)(ap);
  const float4 a01 = *(const float4*)(ap + 4);
  const float4 a10 = *(const float4*)(ap + 32);
  const float4 a11 = *(const float4*)(ap + 36);
  bf16x8 a0, a1;
  a0[0]=f2bf(a00.x); a0[1]=f2bf(a00.y); a0[2]=f2bf(a00.z); a0[3]=f2bf(a00.w);
  a0[4]=f2bf(a01.x); a0[5]=f2bf(a01.y); a0[6]=f2bf(a01.z); a0[7]=f2bf(a01.w);
  a1[0]=f2bf(a10.x); a1[1]=f2bf(a10.y); a1[2]=f2bf(a10.z); a1[3]=f2bf(a10.w);
  a1[4]=f2bf(a11.x); a1[5]=f2bf(a11.y); a1[6]=f2bf(a11.z); a1[7]=f2bf(a11.w);

  f32x4 acc[16];
#pragma unroll
  for (int n = 0; n < 16; ++n) acc[n] = (f32x4){0.f, 0.f, 0.f, 0.f};

#pragma unroll
  for (int n = 0; n < 16; ++n) {
    const unsigned short* bp = wet + (size_t)(n * 16 + lid) * 64 + lg * 8;
    const bf16x8 b0 = *(const bf16x8*)(bp);
    const bf16x8 b1 = *(const bf16x8*)(bp + 32);
    acc[n] = __builtin_amdgcn_mfma_f32_16x16x32_bf16(a0, b0, acc[n], 0, 0, 0);
    acc[n] = __builtin_amdgcn_mfma_f32_16x16x32_bf16(a1, b1, acc[n], 0, 0, 0);
  }

  // per-lane edge rows: r -> edge e0 + 4*lg + r
  int s[4], d[4];
#pragma unroll
  for (int r = 0; r < 4; ++r) {
    const int e = e0 + lg * 4 + r;
    s[r] = src[e]; d[r] = dst[e];
  }

  float plog[4][4];
#pragma unroll
  for (int r = 0; r < 4; ++r)
#pragma unroll
    for (int h = 0; h < 4; ++h) plog[r][h] = 0.f;

#pragma unroll
  for (int n = 0; n < 16; ++n) {
    const int col = n * 16 + lid;
    const float av = att[col];
    const int h = n >> 2;
#pragma unroll
    for (int r = 0; r < 4; ++r) {
      const float xlv = bf2f(xlb[(size_t)s[r] * 256 + col]);
      const float xrv = bf2f(xrb[(size_t)d[r] * 256 + col]);
      float m = acc[n][r] + xlv + xrv;
      m = LRELU(m);
      plog[r][h] += m * av;
    }
  }

  // reduce over the 16 lanes of each lg-group (they hold the 16 col-slices)
#pragma unroll
  for (int r = 0; r < 4; ++r)
#pragma unroll
    for (int h = 0; h < 4; ++h) {
      float v = plog[r][h];
#pragma unroll
      for (int sft = 8; sft >= 1; sft >>= 1) v += __shfl_xor(v, sft, 16);
      plog[r][h] = v;
    }

  // writer: lane lid handles (r = lid&3, h = lid>>2) — cndmask select chain
  float v = 0.f; int dsel = 0;
#pragma unroll
  for (int r = 0; r < 4; ++r)
#pragma unroll
    for (int h = 0; h < 4; ++h)
      if (lid == h * 4 + r) { v = plog[r][h]; dsel = d[r]; }

  const int e = e0 + lg * 4 + (lid & 3);
  const int h = lid >> 2;
  const float ev = expf(v);
  elog[(size_t)e * 4 + h] = ev;
  atomicAdd(&denom[(size_t)dsel * 4 + h], ev);
}

// ---------------------------------------------------------------------------
// CSR build: histogram -> exclusive scan -> bucket fill
// ---------------------------------------------------------------------------
__global__ __launch_bounds__(256)
void dst_hist(const int* __restrict__ dst, int* __restrict__ cnt) {
  const int e = blockIdx.x * 256 + threadIdx.x;
  if (e < NE) atomicAdd(&cnt[dst[e]], 1);
}

__global__ __launch_bounds__(1024)
void exscan(int* __restrict__ cnt, int* __restrict__ row_start,
            int* __restrict__ cur, int n) {
  __shared__ int buf[1024];
  __shared__ int carry;
  if (threadIdx.x == 0) carry = 0;
  __syncthreads();
  for (int base = 0; base < n; base += 1024) {
    const int i = base + threadIdx.x;
    const int v = (i < n) ? cnt[i] : 0;
    buf[threadIdx.x] = v;
    __syncthreads();
    for (int off = 1; off < 1024; off <<= 1) {
      const int t = (threadIdx.x >= off) ? buf[threadIdx.x - off] : 0;
      __syncthreads();
      buf[threadIdx.x] += t;
      __syncthreads();
    }
    const int excl = buf[threadIdx.x] - v + carry;
    if (i < n) { row_start[i] = excl; cur[i] = excl; }
    __syncthreads();
    if (threadIdx.x == 1023) carry += buf[1023];
    __syncthreads();
  }
  if (threadIdx.x == 0) row_start[n] = carry;
}

__global__ __launch_bounds__(256)
void bucket_fill(const int* __restrict__ dst, int* __restrict__ cur,
                 int* __restrict__ eid) {
  const int e = blockIdx.x * 256 + threadIdx.x;
  if (e < NE) {
    const int p = atomicAdd(&cur[dst[e]], 1);
    eid[p] = e;
  }
}

// ---------------------------------------------------------------------------
// Aggregation (gather): one wave per dst node, 4 nodes per block.
// ---------------------------------------------------------------------------
__global__ __launch_bounds__(256)
void aggregate(const float* __restrict__ xl, const float* __restrict__ elog,
               const float* __restrict__ denom, const int* __restrict__ eid,
               const int* __restrict__ row_start, const int* __restrict__ src,
               const float* __restrict__ bias, float* __restrict__ out) {
  const int wid  = threadIdx.x >> 6;
  const int lane = threadIdx.x & 63;
  const int d    = blockIdx.x * 4 + wid;
  if (d >= NN) return;
  const int h = lane >> 4;
  const int c = lane * 4;
  const float invden = 1.f / (denom[(size_t)d * 4 + h] + 1e-16f);
  float4 acc = *(const float4*)(bias + c);
  const int beg = row_start[d], end = row_start[d + 1];
  for (int i = beg; i < end; ++i) {
    const int e = eid[i];
    const int s = src[e];
    const float a = elog[(size_t)e * 4 + h] * invden;
    const float4 v = *(const float4*)(xl + (size_t)s * 256 + c);
    acc.x += a * v.x; acc.y += a * v.y;
    acc.z += a * v.z; acc.w += a * v.w;
  }
  *(float4*)(out + (size_t)d * 256 + c) = acc;
}

extern "C" void kernel_launch(void* const* d_in, const int* in_sizes, int n_in,
                              void* d_out, int out_size, void* d_ws, size_t ws_size,
                              hipStream_t stream) {
  const float* x    = (const float*)d_in[0];
  const int*   ei   = (const int*)d_in[1];
  const float* ea   = (const float*)d_in[2];
  const float* Wl1  = (const float*)d_in[3];
  const float* bl1  = (const float*)d_in[4];
  const float* Wr1  = (const float*)d_in[5];
  const float* br1  = (const float*)d_in[6];
  const float* We1  = (const float*)d_in[7];
  const float* att1 = (const float*)d_in[8];
  const float* bias1= (const float*)d_in[9];
  const float* Wl2  = (const float*)d_in[10];
  const float* bl2  = (const float*)d_in[11];
  const float* Wr2  = (const float*)d_in[12];
  const float* br2  = (const float*)d_in[13];
  const float* We2  = (const float*)d_in[14];
  const float* att2 = (const float*)d_in[15];
  const float* bias2= (const float*)d_in[16];

  float* out = (float*)d_out;
  float* ws  = (float*)d_ws;

  // layout (16B-aligned sections)
  float* xl    = ws;                                   // NN*256
  float* elog  = xl + (size_t)NN * 256;                // NE*4
  float* denom = elog + (size_t)NE * 4;                // NN*4
  unsigned short* xlb  = (unsigned short*)(denom + (size_t)NN * 4); // NN*256
  unsigned short* xrb  = xlb + (size_t)NN * 256;       // NN*256
  unsigned short* wet1 = xrb + (size_t)NN * 256;       // 16384
  unsigned short* wet2 = wet1 + 16384;                 // 16384
  int* cur       = (int*)(wet2 + 16384);               // NN
  int* row_start = cur + NN;                           // NN+1
  int* eid       = row_start + NN + 1;                 // NE
  float* h1 = out;  // d_out doubles as h1

  const int* src = ei;
  const int* dst = ei + NE;

  const dim3 ggrid((NN + 63) / 64, 2);
  const int  egrid = NE / 64;
  const int  epb   = (NE + 255) / 256;
  const int  agrid = (NN + 3) / 4;

  // ---- prep: CSR + WeT bf16 ----
  hipMemsetAsync(cur, 0, NN * sizeof(int), stream);
  conv_wet<<<dim3(64, 2), 256, 0, stream>>>(We1, wet1, We2, wet2);
  dst_hist<<<epb, 256, 0, stream>>>(dst, cur);
  exscan<<<1, 1024, 0, stream>>>(cur, row_start, cur, NN);
  bucket_fill<<<epb, 256, 0, stream>>>(dst, cur, eid);

  // ---- layer 1 ----
  gemm_bias2<<<ggrid, 256, 0, stream>>>(x, Wl1, bl1, xl, xlb, Wr1, br1, xrb,
                                        NN, 128);
  hipMemsetAsync(denom, 0, (size_t)NN * 4 * sizeof(float), stream);
  edge_logits_mfma<<<egrid, 256, 0, stream>>>(ea, wet1, xlb, xrb, att1,
                                              src, dst, elog, denom);
  aggregate<<<agrid, 256, 0, stream>>>(xl, elog, denom, eid, row_start, src,
                                       bias1, h1);

  // ---- layer 2 ----
  gemm_bias2<<<ggrid, 256, 0, stream>>>(h1, Wl2, bl2, xl, xlb, Wr2, br2, xrb,
                                        NN, 256);
  hipMemsetAsync(denom, 0, (size_t)NN * 4 * sizeof(float), stream);
  edge_logits_mfma<<<egrid, 256, 0, stream>>>(ea, wet2, xlb, xrb, att2,
                                              src, dst, elog, denom);
  aggregate<<<agrid, 256, 0, stream>>>(xl, elog, denom, eid, row_start, src,
                                       bias2, out);
}